// Round 2
// baseline (567.687 us; speedup 1.0000x reference)
//
#include <hip/hip_runtime.h>

// CRF forward (Viterbi + partition) for B=512, S=2048, L=17.
// Serial-scan latency problem: wall-clock = 2048 x per-step chain of the
// slowest wave. Grid 1024 x 64thr = 1 wave/SIMD on 256 CUs (LDS 37KB -> exactly
// 4 blocks/CU). Blocks 0..511: Viterbi (bit-exact vs reference: same fp32 add
// order, exact max, first-max-wins argmax). Blocks 512..1023: partition scan.
//
// Viterbi per-step: i-reduction split across wave halves (h=0: i in [0,9),
// h=1: i in [9,17) + -inf pad). Broadcast of prev scores via 9 ds_bpermute;
// tree argmax (left-wins tie within half, half0-wins across halves == global
// first-max-wins); cross-half combine via 2 bpermutes (lane^32). Backpointers
// in LDS (byte), in-block backtrace via readlane chain.
//
// Partition per-step (log2 domain, x pre-scaled by log2e at refill):
//   s_j = sum_i exp2(z_i) * E_ij  (E = exp(A), readlane broadcast, fma tree)
//   w_j = log2(s_j) + x2_t_j ; z_j = w_j - w_0 ; base += (double)w_0
// Normalizing by the CURRENT w_0 keeps |z| <= cross-label spread (~8) --
// the round-0 "lagged delta" was an undamped resonator (u_t = dW + u_{t-1}
// - u_{t-2}, roots e^{+-i pi/3}) with exp-overflow tail risk. Z recovered as
// (base + log2(sum exp2 z)) * ln2 in double.

constexpr int NL = 17;
constexpr int NS = 2048;
constexpr int NB = 512;

#define LOG2EF 1.4426950408889634f

__device__ __forceinline__ float readlane_f(float v, int l) {
  return __int_as_float(__builtin_amdgcn_readlane(__float_as_int(v), l));
}
__device__ __forceinline__ float bperm_f(int idx4, float v) {
  return __int_as_float(__builtin_amdgcn_ds_bpermute(idx4, __float_as_int(v)));
}

// first-max-wins select: B must carry the HIGHER global index; strict > keeps A
#define SEL(vA, iA, vB, iB, vO, iO)              \
  {                                              \
    bool g_ = (vB) > (vA);                       \
    (vO) = g_ ? (vB) : (vA);                     \
    (iO) = g_ ? (iB) : (iA);                     \
  }

__global__ __launch_bounds__(64, 1) void crf_fwd_kernel(
    const float* __restrict__ x, const float* __restrict__ A,
    float* __restrict__ preds, double* __restrict__ wsZ) {
  __shared__ unsigned char bp[NS * NL + 128];  // rows t=1..NS-1 + dummy pad
  __shared__ unsigned char labs[NS + 72];

  const int bid = blockIdx.x;
  const int lane = threadIdx.x;

  if (bid < NB) {
    // ================= Viterbi =================
    const float* xb = x + (size_t)bid * (NS * NL);
    const bool isH1 = (lane >= 32);
    const int jr = lane & 31;
    const int j = (jr < NL) ? jr : 0;  // clamped dup for idle lanes
    const int i0 = isH1 ? 9 : 0;

    float a[9];
    int idx4[9];
#pragma unroll
    for (int k = 0; k < 9; ++k) {
      int i = i0 + k;
      bool real = (i < NL);
      a[k] = real ? A[(real ? i : 0) * NL + j] : -INFINITY;
      idx4[k] = (real ? i : 0) << 2;
    }
    const int xidx4 = (lane ^ 32) << 2;

    const bool wr = (!isH1) && (jr < NL);
    int bpa = wr ? (NL + jr) : (NS * NL + lane);  // t=1 row base (or dummy)
    const int bps4 = wr ? 4 * NL : 0;

    float cur = xb[j];  // init = x[:,0,:]
    float xr0 = xb[1 * NL + j];
    float xr1 = xb[2 * NL + j];
    float xr2 = xb[3 * NL + j];
    float xr3 = xb[4 * NL + j];

    auto vstep = [&](float& xr, int t, int off) {
      float p[9];
#pragma unroll
      for (int k = 0; k < 9; ++k) p[k] = bperm_f(idx4[k], cur) + a[k];
      // tree argmax over this half's 9 candidates (indices i0+k ascending)
      float q0, q1, q2, q3, u0, u1, w;
      int c0, c1, c2, c3, d0, d1, e;
      SEL(p[0], i0 + 0, p[1], i0 + 1, q0, c0);
      SEL(p[2], i0 + 2, p[3], i0 + 3, q1, c1);
      SEL(p[4], i0 + 4, p[5], i0 + 5, q2, c2);
      SEL(p[6], i0 + 6, p[7], i0 + 7, q3, c3);
      SEL(q0, c0, q1, c1, u0, d0);
      SEL(q2, c2, q3, c3, u1, d1);
      SEL(u0, d0, u1, d1, w, e);
      float m;
      int mi;
      SEL(w, e, p[8], i0 + 8, m, mi);
      // cross-half combine: half0 candidate = lower indices, wins ties
      float mo = bperm_f(xidx4, m);
      int mio = __builtin_amdgcn_ds_bpermute(xidx4, mi);
      float vlo = isH1 ? mo : m;
      float vhi = isH1 ? m : mo;
      int ilo = isH1 ? mio : mi;
      int ihi = isH1 ? mi : mio;
      bool gt = vhi > vlo;  // strict: half0 wins ties (lower index)
      float best = gt ? vhi : vlo;
      int bi = gt ? ihi : ilo;
      cur = best + xr;
      bp[bpa + off] = (unsigned char)bi;
      int tn = t + 4;
      tn = (tn <= NS - 1) ? tn : (NS - 1);
      xr = xb[tn * NL + j];  // ring refill (clamped: no OOB on last batch)
    };

    for (int tb = 1; tb + 3 < NS; tb += 4) {
      vstep(xr0, tb, 0);
      vstep(xr1, tb + 1, NL);
      vstep(xr2, tb + 2, 2 * NL);
      vstep(xr3, tb + 3, 3 * NL);
      bpa += bps4;
    }
    vstep(xr0, NS - 3, 0);
    vstep(xr1, NS - 2, NL);
    vstep(xr2, NS - 1, 2 * NL);

    // final argmax over j (cur_j lives in lanes 0..16)
    float bv = readlane_f(cur, 0);
    int bl = 0;
#pragma unroll
    for (int i = 1; i < NL; ++i) {
      float v = readlane_f(cur, i);
      if (v > bv) { bv = v; bl = i; }
    }

    // ================= backtrace =================
    const int labsDummy = NS + lane;
    int lab = bl;
    labs[(lane == 0) ? (NS - 1) : labsDummy] = (unsigned char)lab;
    int rr0 = bp[(NS - 1) * NL + j];
    int rr1 = bp[(NS - 2) * NL + j];
    int rr2 = bp[(NS - 3) * NL + j];
    int rr3 = bp[(NS - 4) * NL + j];
    for (int tb = NS - 1; tb >= 4; tb -= 4) {
      int pt;
      lab = __builtin_amdgcn_readlane(rr0, lab);
      labs[(lane == 0) ? (tb - 1) : labsDummy] = (unsigned char)lab;
      pt = tb - 4; rr0 = bp[(pt >= 1 ? pt : 1) * NL + j];
      lab = __builtin_amdgcn_readlane(rr1, lab);
      labs[(lane == 0) ? (tb - 2) : labsDummy] = (unsigned char)lab;
      pt = tb - 5; rr1 = bp[(pt >= 1 ? pt : 1) * NL + j];
      lab = __builtin_amdgcn_readlane(rr2, lab);
      labs[(lane == 0) ? (tb - 3) : labsDummy] = (unsigned char)lab;
      pt = tb - 6; rr2 = bp[(pt >= 1 ? pt : 1) * NL + j];
      lab = __builtin_amdgcn_readlane(rr3, lab);
      labs[(lane == 0) ? (tb - 4) : labsDummy] = (unsigned char)lab;
      pt = tb - 7; rr3 = bp[(pt >= 1 ? pt : 1) * NL + j];
    }
    lab = __builtin_amdgcn_readlane(rr0, lab);  // row 3 -> labs[2]
    labs[(lane == 0) ? 2 : labsDummy] = (unsigned char)lab;
    lab = __builtin_amdgcn_readlane(rr1, lab);  // row 2 -> labs[1]
    labs[(lane == 0) ? 1 : labsDummy] = (unsigned char)lab;
    lab = __builtin_amdgcn_readlane(rr2, lab);  // row 1 -> labs[0]
    labs[(lane == 0) ? 0 : labsDummy] = (unsigned char)lab;

    float* pb = preds + (size_t)bid * NS;
    for (int k = lane; k < NS; k += 64) pb[k] = (float)labs[k];
  } else {
    // ================= partition (log-Z), log2 domain =================
    const int b = bid - NB;
    const float* xb = x + (size_t)b * (NS * NL);
    const int j = lane % NL;  // lanes 0..16 carry the real state

    float E[NL];
#pragma unroll
    for (int i = 0; i < NL; ++i)
      E[i] = __builtin_amdgcn_exp2f(A[i * NL + j] * LOG2EF);  // e^A_ij

    float g = __builtin_amdgcn_exp2f(xb[j] * LOG2EF);  // exp2(z), z=x0*log2e
    double base = 0.0;                                 // accumulated w0 (log2)
    float xr0 = xb[1 * NL + j] * LOG2EF;
    float xr1 = xb[2 * NL + j] * LOG2EF;
    float xr2 = xb[3 * NL + j] * LOG2EF;
    float xr3 = xb[4 * NL + j] * LOG2EF;

    auto pstep = [&](float& xr, int t) {
      float gg[NL];
#pragma unroll
      for (int i = 0; i < NL; ++i) gg[i] = readlane_f(g, i);
      float s0 = gg[0] * E[0];
      float s1 = gg[1] * E[1];
      float s2 = gg[2] * E[2];
      float s3 = gg[3] * E[3];
#pragma unroll
      for (int i = 4; i + 3 < NL; i += 4) {
        s0 = fmaf(gg[i + 0], E[i + 0], s0);
        s1 = fmaf(gg[i + 1], E[i + 1], s1);
        s2 = fmaf(gg[i + 2], E[i + 2], s2);
        s3 = fmaf(gg[i + 3], E[i + 3], s3);
      }
      s0 = fmaf(gg[16], E[16], s0);
      float s = (s0 + s1) + (s2 + s3);
      float w = __builtin_amdgcn_logf(s) + xr;  // log2(s) + x*log2e
      float w0 = readlane_f(w, 0);              // CURRENT-step normalizer
      base += (double)w0;                       // exact offset accumulation
      g = __builtin_amdgcn_exp2f(w - w0);       // |w-w0| <= label spread (~8)
      int tn = t + 4;
      tn = (tn <= NS - 1) ? tn : (NS - 1);
      xr = xb[tn * NL + j] * LOG2EF;
    };

    for (int tb = 1; tb + 3 < NS; tb += 4) {
      pstep(xr0, tb);
      pstep(xr1, tb + 1);
      pstep(xr2, tb + 2);
      pstep(xr3, tb + 3);
    }
    pstep(xr0, NS - 3);
    pstep(xr1, NS - 2);
    pstep(xr2, NS - 1);

    float sg = readlane_f(g, 0);
#pragma unroll
    for (int i = 1; i < NL; ++i) sg += readlane_f(g, i);
    if (lane == 0)
      wsZ[b] = (base + (double)__builtin_amdgcn_logf(sg)) *
               0.6931471805599453;  // log2 -> ln
  }
}

__global__ __launch_bounds__(64, 1) void crf_nll_kernel(
    const float* __restrict__ x, const int* __restrict__ y,
    const float* __restrict__ A, const double* __restrict__ wsZ,
    double* __restrict__ wsP) {
  const int b = blockIdx.x;
  const int lane = threadIdx.x;
  const float* xb = x + (size_t)b * (NS * NL);
  const int* yb = y + (size_t)b * NS;
  float sum = 0.f;
  for (int t = lane; t < NS; t += 64) {
    int yt = yb[t];
    sum += xb[t * NL + yt];                     // emission gather
    if (t >= 1) sum += A[yt * NL + yb[t - 1]];  // transition gather
  }
#pragma unroll
  for (int off = 32; off >= 1; off >>= 1) sum += __shfl_xor(sum, off);
  if (lane == 0) wsP[b] = wsZ[b] - (double)sum;  // -(emis+trans) + Z
}

__global__ __launch_bounds__(512, 1) void crf_final_kernel(
    const double* __restrict__ wsP, float* __restrict__ outNll) {
  __shared__ double sm[NB];
  const int i = threadIdx.x;
  sm[i] = wsP[i];
  __syncthreads();
  for (int off = NB / 2; off >= 1; off >>= 1) {
    if (i < off) sm[i] += sm[i + off];
    __syncthreads();
  }
  if (i == 0) outNll[0] = (float)(sm[0] * (1.0 / NB));
}

extern "C" void kernel_launch(void* const* d_in, const int* in_sizes, int n_in,
                              void* d_out, int out_size, void* d_ws,
                              size_t ws_size, hipStream_t stream) {
  const float* x = (const float*)d_in[0];
  const int* y = (const int*)d_in[1];  // harness delivers integers as int32
  const float* A = (const float*)d_in[2];
  float* out = (float*)d_out;   // [B*S] preds-as-float, then nll scalar
  double* wsZ = (double*)d_ws;  // [512] log-partition per batch
  double* wsP = wsZ + NB;       // [512] per-batch nll

  crf_fwd_kernel<<<dim3(2 * NB), dim3(64), 0, stream>>>(x, A, out, wsZ);
  crf_nll_kernel<<<dim3(NB), dim3(64), 0, stream>>>(x, y, A, wsZ, wsP);
  crf_final_kernel<<<dim3(1), dim3(512), 0, stream>>>(wsP,
                                                      out + (size_t)NB * NS);
}

// Round 3
// 514.875 us; speedup vs baseline: 1.1026x; 1.1026x over previous
//
#include <hip/hip_runtime.h>

// CRF forward (Viterbi + partition) for B=512, S=2048, L=17.
// Serial-scan latency problem. Grid 1024 x 64thr, LDS 37KB -> 4 blocks/CU ->
// 1 wave/SIMD. Blocks 0..511 Viterbi, 512..1023 partition.
//
// Round-2 counters: fwd=466us, VALUBusy=30%, 546 cy/step => DS-latency bound
// (11 ds_bpermute/step, 2 dependent DS round-trips + 4 waves sharing one LDS
// pipe). Round-3: all-VALU step -- v_readlane broadcast of prev state into
// SGPRs (uniform => legal single-SGPR operand of v_add_f32), per-lane 16-SEL
// tree argmax (ascending pairs, left-wins-tie == jnp.argmax first-max-wins;
// label 16 merged last as right operand, strict >). ~90 VALU/step ~= 185cy
// issue-bound; latency chain ~60cy. Predicted fwd ~170us, VALUBusy 75-90%.
//
// Partition (validated exact): log2-domain factored scan
//   s_j = sum_i exp2(z_i)*E_ij ; w = log2(s)+x*log2e ; z = w - w0 ;
//   base += (double)w0  (current-step normalizer keeps |z| <= label spread).

constexpr int NL = 17;
constexpr int NS = 2048;
constexpr int NB = 512;

#define LOG2EF 1.4426950408889634f

__device__ __forceinline__ float readlane_f(float v, int l) {
  return __int_as_float(__builtin_amdgcn_readlane(__float_as_int(v), l));
}

// first-max-wins select: B must carry the HIGHER index; strict > keeps A on tie
#define SEL(vA, iA, vB, iB, vO, iO)              \
  {                                              \
    bool g_ = (vB) > (vA);                       \
    (vO) = g_ ? (vB) : (vA);                     \
    (iO) = g_ ? (iB) : (iA);                     \
  }

__global__ __launch_bounds__(64, 1) void crf_fwd_kernel(
    const float* __restrict__ x, const float* __restrict__ A,
    float* __restrict__ preds, double* __restrict__ wsZ) {
  __shared__ unsigned char bp[NS * NL + 128];  // rows t=1..NS-1 + dummy pad
  __shared__ unsigned char labs[NS + 72];

  const int bid = blockIdx.x;
  const int lane = threadIdx.x;
  const int j = lane % NL;  // lanes 17..63 compute harmless dups of j=lane%17

  if (bid < NB) {
    // ================= Viterbi =================
    const float* xb = x + (size_t)bid * (NS * NL);
    float a[NL];
#pragma unroll
    for (int i = 0; i < NL; ++i) a[i] = A[i * NL + j];

    const bool wr = (lane < NL);
    int bpa = wr ? (NL + lane) : (NS * NL + lane);  // t=1 row base (or dummy)
    const int bps4 = wr ? 4 * NL : 0;

    float cur = xb[j];  // init = x[:,0,:]  (same fp32 path as reference)
    float xr0 = xb[1 * NL + j];
    float xr1 = xb[2 * NL + j];
    float xr2 = xb[3 * NL + j];
    float xr3 = xb[4 * NL + j];

    auto vstep = [&](float& xr, int t, int off) {
      float p[NL];
#pragma unroll
      for (int i = 0; i < NL; ++i) p[i] = readlane_f(cur, i) + a[i];
      // 16-SEL tree argmax, ascending-index pairs (first-max-wins exact)
      float q[8];
      int qi[8];
#pragma unroll
      for (int k = 0; k < 8; ++k)
        SEL(p[2 * k], 2 * k, p[2 * k + 1], 2 * k + 1, q[k], qi[k]);
      float r[4];
      int ri[4];
#pragma unroll
      for (int k = 0; k < 4; ++k)
        SEL(q[2 * k], qi[2 * k], q[2 * k + 1], qi[2 * k + 1], r[k], ri[k]);
      float u0, u1, w, best;
      int d0, d1, e, bi;
      SEL(r[0], ri[0], r[1], ri[1], u0, d0);
      SEL(r[2], ri[2], r[3], ri[3], u1, d1);
      SEL(u0, d0, u1, d1, w, e);
      SEL(w, e, p[16], 16, best, bi);  // label 16 last, right operand
      cur = best + xr;
      bp[bpa + off] = (unsigned char)bi;
      int tn = t + 4;
      tn = (tn <= NS - 1) ? tn : (NS - 1);
      xr = xb[tn * NL + j];  // ring refill (clamped; harmless dup loads at end)
    };

    for (int tb = 1; tb + 3 < NS; tb += 4) {
      vstep(xr0, tb, 0);
      vstep(xr1, tb + 1, NL);
      vstep(xr2, tb + 2, 2 * NL);
      vstep(xr3, tb + 3, 3 * NL);
      bpa += bps4;
    }
    vstep(xr0, NS - 3, 0);
    vstep(xr1, NS - 2, NL);
    vstep(xr2, NS - 1, 2 * NL);

    // final argmax over j (cur_j lives in lanes 0..16)
    float bv = readlane_f(cur, 0);
    int bl = 0;
#pragma unroll
    for (int i = 1; i < NL; ++i) {
      float v = readlane_f(cur, i);
      if (v > bv) { bv = v; bl = i; }
    }

    // ================= backtrace =================
    const int labsDummy = NS + lane;
    int lab = bl;
    labs[(lane == 0) ? (NS - 1) : labsDummy] = (unsigned char)lab;
    int rr0 = bp[(NS - 1) * NL + j];
    int rr1 = bp[(NS - 2) * NL + j];
    int rr2 = bp[(NS - 3) * NL + j];
    int rr3 = bp[(NS - 4) * NL + j];
    for (int tb = NS - 1; tb >= 4; tb -= 4) {
      int pt;
      lab = __builtin_amdgcn_readlane(rr0, lab);
      labs[(lane == 0) ? (tb - 1) : labsDummy] = (unsigned char)lab;
      pt = tb - 4; rr0 = bp[(pt >= 1 ? pt : 1) * NL + j];
      lab = __builtin_amdgcn_readlane(rr1, lab);
      labs[(lane == 0) ? (tb - 2) : labsDummy] = (unsigned char)lab;
      pt = tb - 5; rr1 = bp[(pt >= 1 ? pt : 1) * NL + j];
      lab = __builtin_amdgcn_readlane(rr2, lab);
      labs[(lane == 0) ? (tb - 3) : labsDummy] = (unsigned char)lab;
      pt = tb - 6; rr2 = bp[(pt >= 1 ? pt : 1) * NL + j];
      lab = __builtin_amdgcn_readlane(rr3, lab);
      labs[(lane == 0) ? (tb - 4) : labsDummy] = (unsigned char)lab;
      pt = tb - 7; rr3 = bp[(pt >= 1 ? pt : 1) * NL + j];
    }
    lab = __builtin_amdgcn_readlane(rr0, lab);  // row 3 -> labs[2]
    labs[(lane == 0) ? 2 : labsDummy] = (unsigned char)lab;
    lab = __builtin_amdgcn_readlane(rr1, lab);  // row 2 -> labs[1]
    labs[(lane == 0) ? 1 : labsDummy] = (unsigned char)lab;
    lab = __builtin_amdgcn_readlane(rr2, lab);  // row 1 -> labs[0]
    labs[(lane == 0) ? 0 : labsDummy] = (unsigned char)lab;

    float* pb = preds + (size_t)bid * NS;
    for (int k = lane; k < NS; k += 64) pb[k] = (float)labs[k];
  } else {
    // ================= partition (log-Z), log2 domain =================
    const int b = bid - NB;
    const float* xb = x + (size_t)b * (NS * NL);

    float E[NL];
#pragma unroll
    for (int i = 0; i < NL; ++i)
      E[i] = __builtin_amdgcn_exp2f(A[i * NL + j] * LOG2EF);  // e^A_ij

    float g = __builtin_amdgcn_exp2f(xb[j] * LOG2EF);  // exp2(z), z=x0*log2e
    double base = 0.0;                                 // accumulated w0 (log2)
    float xr0 = xb[1 * NL + j] * LOG2EF;
    float xr1 = xb[2 * NL + j] * LOG2EF;
    float xr2 = xb[3 * NL + j] * LOG2EF;
    float xr3 = xb[4 * NL + j] * LOG2EF;

    auto pstep = [&](float& xr, int t) {
      float gg[NL];
#pragma unroll
      for (int i = 0; i < NL; ++i) gg[i] = readlane_f(g, i);
      float s0 = gg[0] * E[0];
      float s1 = gg[1] * E[1];
      float s2 = gg[2] * E[2];
      float s3 = gg[3] * E[3];
#pragma unroll
      for (int i = 4; i + 3 < NL; i += 4) {
        s0 = fmaf(gg[i + 0], E[i + 0], s0);
        s1 = fmaf(gg[i + 1], E[i + 1], s1);
        s2 = fmaf(gg[i + 2], E[i + 2], s2);
        s3 = fmaf(gg[i + 3], E[i + 3], s3);
      }
      s0 = fmaf(gg[16], E[16], s0);
      float s = (s0 + s1) + (s2 + s3);
      float w = __builtin_amdgcn_logf(s) + xr;  // log2(s) + x*log2e
      float w0 = readlane_f(w, 0);              // CURRENT-step normalizer
      base += (double)w0;                       // exact offset accumulation
      g = __builtin_amdgcn_exp2f(w - w0);       // |w-w0| <= label spread
      int tn = t + 4;
      tn = (tn <= NS - 1) ? tn : (NS - 1);
      xr = xb[tn * NL + j] * LOG2EF;
    };

    for (int tb = 1; tb + 3 < NS; tb += 4) {
      pstep(xr0, tb);
      pstep(xr1, tb + 1);
      pstep(xr2, tb + 2);
      pstep(xr3, tb + 3);
    }
    pstep(xr0, NS - 3);
    pstep(xr1, NS - 2);
    pstep(xr2, NS - 1);

    float sg = readlane_f(g, 0);
#pragma unroll
    for (int i = 1; i < NL; ++i) sg += readlane_f(g, i);
    if (lane == 0)
      wsZ[b] = (base + (double)__builtin_amdgcn_logf(sg)) *
               0.6931471805599453;  // log2 -> ln
  }
}

__global__ __launch_bounds__(64, 1) void crf_nll_kernel(
    const float* __restrict__ x, const int* __restrict__ y,
    const float* __restrict__ A, const double* __restrict__ wsZ,
    double* __restrict__ wsP) {
  const int b = blockIdx.x;
  const int lane = threadIdx.x;
  const float* xb = x + (size_t)b * (NS * NL);
  const int* yb = y + (size_t)b * NS;
  float sum = 0.f;
  for (int t = lane; t < NS; t += 64) {
    int yt = yb[t];
    sum += xb[t * NL + yt];                     // emission gather
    if (t >= 1) sum += A[yt * NL + yb[t - 1]];  // transition gather
  }
#pragma unroll
  for (int off = 32; off >= 1; off >>= 1) sum += __shfl_xor(sum, off);
  if (lane == 0) wsP[b] = wsZ[b] - (double)sum;  // -(emis+trans) + Z
}

__global__ __launch_bounds__(512, 1) void crf_final_kernel(
    const double* __restrict__ wsP, float* __restrict__ outNll) {
  __shared__ double sm[NB];
  const int i = threadIdx.x;
  sm[i] = wsP[i];
  __syncthreads();
  for (int off = NB / 2; off >= 1; off >>= 1) {
    if (i < off) sm[i] += sm[i + off];
    __syncthreads();
  }
  if (i == 0) outNll[0] = (float)(sm[0] * (1.0 / NB));
}

extern "C" void kernel_launch(void* const* d_in, const int* in_sizes, int n_in,
                              void* d_out, int out_size, void* d_ws,
                              size_t ws_size, hipStream_t stream) {
  const float* x = (const float*)d_in[0];
  const int* y = (const int*)d_in[1];  // harness delivers integers as int32
  const float* A = (const float*)d_in[2];
  float* out = (float*)d_out;   // [B*S] preds-as-float, then nll scalar
  double* wsZ = (double*)d_ws;  // [512] log-partition per batch
  double* wsP = wsZ + NB;       // [512] per-batch nll

  crf_fwd_kernel<<<dim3(2 * NB), dim3(64), 0, stream>>>(x, A, out, wsZ);
  crf_nll_kernel<<<dim3(NB), dim3(64), 0, stream>>>(x, y, A, wsZ, wsP);
  crf_final_kernel<<<dim3(1), dim3(512), 0, stream>>>(wsP,
                                                      out + (size_t)NB * NS);
}

// Round 4
// 514.669 us; speedup vs baseline: 1.1030x; 1.0004x over previous
//
#include <hip/hip_runtime.h>

// CRF forward (Viterbi + partition) for B=512, S=2048, L=17.
// Geometry is pinned: 1024 serial chains on 1024 SIMDs (1 wave each, grid
// 1024x64, LDS 37KB -> 4 blocks/CU). Wall = per-step issue + unhidden stalls.
//
// Round-3 counters: fwd=417us (489 cy/step), VALUBusy=50%. Issue ~245cy
// (SEL tree = cmp+2*cndmask x16 + 17 readlane + 17 add), stalls ~245cy
// (vcc/SGPR hazards, no TLP to hide them). Round-4: split value path from
// index path. Value: pure v_max3 tree (9 insts, 12cy chain) -> cur = m + xr
// (bit-exact fp32 adds, exact max). Index: reverse eq-scan
// (bi = p[k]==m ? k : bi, k=15..0 after init bi=16) -- exact first-max-wins
// (smallest index written last), 32 insts OFF the value chain; overlaps with
// next step's readlanes under the 4x unroll. Predicted ~150-170cy issue/step.
//
// nll gather split 4x: 2048 blocks x 512 timesteps -> partials wsS[2048];
// final kernel combines (rounding regrouped; preds remain bit-exact).
//
// Partition (validated exact, absmax 0): log2-domain factored scan,
// current-step w0 normalizer, double base accumulator.

constexpr int NL = 17;
constexpr int NS = 2048;
constexpr int NB = 512;

#define LOG2EF 1.4426950408889634f

__device__ __forceinline__ float readlane_f(float v, int l) {
  return __int_as_float(__builtin_amdgcn_readlane(__float_as_int(v), l));
}
__device__ __forceinline__ float fmax3(float a, float b, float c) {
  return fmaxf(fmaxf(a, b), c);  // clang fuses to v_max3_f32
}

__global__ __launch_bounds__(64, 1) void crf_fwd_kernel(
    const float* __restrict__ x, const float* __restrict__ A,
    float* __restrict__ preds, double* __restrict__ wsZ) {
  __shared__ unsigned char bp[NS * NL + 128];  // rows t=1..NS-1 + dummy pad
  __shared__ unsigned char labs[NS + 72];

  const int bid = blockIdx.x;
  const int lane = threadIdx.x;
  const int j = lane % NL;  // lanes 17..63 compute harmless dups

  if (bid < NB) {
    // ================= Viterbi =================
    const float* xb = x + (size_t)bid * (NS * NL);
    float a[NL];
#pragma unroll
    for (int i = 0; i < NL; ++i) a[i] = A[i * NL + j];

    const bool wr = (lane < NL);
    int bpa = wr ? (NL + lane) : (NS * NL + lane);  // t=1 row base (or dummy)
    const int bps4 = wr ? 4 * NL : 0;

    float cur = xb[j];  // init = x[:,0,:] (same fp32 path as reference)
    float xr0 = xb[1 * NL + j];
    float xr1 = xb[2 * NL + j];
    float xr2 = xb[3 * NL + j];
    float xr3 = xb[4 * NL + j];

    auto vstep = [&](float& xr, int t, int off) {
      float p[NL];
#pragma unroll
      for (int i = 0; i < NL; ++i) p[i] = readlane_f(cur, i) + a[i];
      // ---- value path: pure max tree (v_max3), chain ~3 levels ----
      float m0 = fmax3(p[0], p[1], p[2]);
      float m1 = fmax3(p[3], p[4], p[5]);
      float m2 = fmax3(p[6], p[7], p[8]);
      float m3 = fmax3(p[9], p[10], p[11]);
      float m4 = fmax3(p[12], p[13], p[14]);
      float m5 = fmaxf(p[15], p[16]);
      float m = fmaxf(fmax3(m0, m1, m2), fmax3(m3, m4, m5));
      cur = m + xr;  // next state -- releases next step's readlanes early
      // ---- index path (off value chain): first k with p[k]==m ----
      int bi = 16;
#pragma unroll
      for (int k = 15; k >= 0; --k) bi = (p[k] == m) ? k : bi;
      bp[bpa + off] = (unsigned char)bi;
      int tn = t + 4;
      tn = (tn <= NS - 1) ? tn : (NS - 1);
      xr = xb[tn * NL + j];  // ring refill (clamped dup loads at tail)
    };

    for (int tb = 1; tb + 3 < NS; tb += 4) {
      vstep(xr0, tb, 0);
      vstep(xr1, tb + 1, NL);
      vstep(xr2, tb + 2, 2 * NL);
      vstep(xr3, tb + 3, 3 * NL);
      bpa += bps4;
    }
    vstep(xr0, NS - 3, 0);
    vstep(xr1, NS - 2, NL);
    vstep(xr2, NS - 1, 2 * NL);

    // final argmax over j (cur_j lives in lanes 0..16), first-max-wins
    float bv = readlane_f(cur, 0);
    int bl = 0;
#pragma unroll
    for (int i = 1; i < NL; ++i) {
      float v = readlane_f(cur, i);
      if (v > bv) { bv = v; bl = i; }
    }

    // ================= backtrace =================
    const int labsDummy = NS + lane;
    int lab = bl;
    labs[(lane == 0) ? (NS - 1) : labsDummy] = (unsigned char)lab;
    int rr0 = bp[(NS - 1) * NL + j];
    int rr1 = bp[(NS - 2) * NL + j];
    int rr2 = bp[(NS - 3) * NL + j];
    int rr3 = bp[(NS - 4) * NL + j];
    for (int tb = NS - 1; tb >= 4; tb -= 4) {
      int pt;
      lab = __builtin_amdgcn_readlane(rr0, lab);
      labs[(lane == 0) ? (tb - 1) : labsDummy] = (unsigned char)lab;
      pt = tb - 4; rr0 = bp[(pt >= 1 ? pt : 1) * NL + j];
      lab = __builtin_amdgcn_readlane(rr1, lab);
      labs[(lane == 0) ? (tb - 2) : labsDummy] = (unsigned char)lab;
      pt = tb - 5; rr1 = bp[(pt >= 1 ? pt : 1) * NL + j];
      lab = __builtin_amdgcn_readlane(rr2, lab);
      labs[(lane == 0) ? (tb - 3) : labsDummy] = (unsigned char)lab;
      pt = tb - 6; rr2 = bp[(pt >= 1 ? pt : 1) * NL + j];
      lab = __builtin_amdgcn_readlane(rr3, lab);
      labs[(lane == 0) ? (tb - 4) : labsDummy] = (unsigned char)lab;
      pt = tb - 7; rr3 = bp[(pt >= 1 ? pt : 1) * NL + j];
    }
    lab = __builtin_amdgcn_readlane(rr0, lab);  // row 3 -> labs[2]
    labs[(lane == 0) ? 2 : labsDummy] = (unsigned char)lab;
    lab = __builtin_amdgcn_readlane(rr1, lab);  // row 2 -> labs[1]
    labs[(lane == 0) ? 1 : labsDummy] = (unsigned char)lab;
    lab = __builtin_amdgcn_readlane(rr2, lab);  // row 1 -> labs[0]
    labs[(lane == 0) ? 0 : labsDummy] = (unsigned char)lab;

    float* pb = preds + (size_t)bid * NS;
    for (int k = lane; k < NS; k += 64) pb[k] = (float)labs[k];
  } else {
    // ================= partition (log-Z), log2 domain =================
    const int b = bid - NB;
    const float* xb = x + (size_t)b * (NS * NL);

    float E[NL];
#pragma unroll
    for (int i = 0; i < NL; ++i)
      E[i] = __builtin_amdgcn_exp2f(A[i * NL + j] * LOG2EF);  // e^A_ij

    float g = __builtin_amdgcn_exp2f(xb[j] * LOG2EF);  // exp2(z)
    double base = 0.0;                                 // accumulated w0 (log2)
    float xr0 = xb[1 * NL + j] * LOG2EF;
    float xr1 = xb[2 * NL + j] * LOG2EF;
    float xr2 = xb[3 * NL + j] * LOG2EF;
    float xr3 = xb[4 * NL + j] * LOG2EF;

    auto pstep = [&](float& xr, int t) {
      float gg[NL];
#pragma unroll
      for (int i = 0; i < NL; ++i) gg[i] = readlane_f(g, i);
      float s0 = gg[0] * E[0];
      float s1 = gg[1] * E[1];
      float s2 = gg[2] * E[2];
      float s3 = gg[3] * E[3];
#pragma unroll
      for (int i = 4; i + 3 < NL; i += 4) {
        s0 = fmaf(gg[i + 0], E[i + 0], s0);
        s1 = fmaf(gg[i + 1], E[i + 1], s1);
        s2 = fmaf(gg[i + 2], E[i + 2], s2);
        s3 = fmaf(gg[i + 3], E[i + 3], s3);
      }
      s0 = fmaf(gg[16], E[16], s0);
      float s = (s0 + s1) + (s2 + s3);
      float w = __builtin_amdgcn_logf(s) + xr;  // log2(s) + x*log2e
      float w0 = readlane_f(w, 0);              // current-step normalizer
      base += (double)w0;                       // exact offset accumulation
      g = __builtin_amdgcn_exp2f(w - w0);       // |w-w0| <= label spread
      int tn = t + 4;
      tn = (tn <= NS - 1) ? tn : (NS - 1);
      xr = xb[tn * NL + j] * LOG2EF;
    };

    for (int tb = 1; tb + 3 < NS; tb += 4) {
      pstep(xr0, tb);
      pstep(xr1, tb + 1);
      pstep(xr2, tb + 2);
      pstep(xr3, tb + 3);
    }
    pstep(xr0, NS - 3);
    pstep(xr1, NS - 2);
    pstep(xr2, NS - 1);

    float sg = readlane_f(g, 0);
#pragma unroll
    for (int i = 1; i < NL; ++i) sg += readlane_f(g, i);
    if (lane == 0)
      wsZ[b] = (base + (double)__builtin_amdgcn_logf(sg)) *
               0.6931471805599453;  // log2 -> ln
  }
}

// 4 blocks per batch, 512 timesteps each -> partial (emis+trans) sums
__global__ __launch_bounds__(64, 1) void crf_gather_kernel(
    const float* __restrict__ x, const int* __restrict__ y,
    const float* __restrict__ A, float* __restrict__ wsS) {
  const int bq = blockIdx.x;
  const int b = bq >> 2;
  const int q = bq & 3;
  const int lane = threadIdx.x;
  const float* xb = x + (size_t)b * (NS * NL);
  const int* yb = y + (size_t)b * NS;
  const int t0 = q * 512;
  float sum = 0.f;
#pragma unroll
  for (int it = 0; it < 8; ++it) {
    int t = t0 + it * 64 + lane;
    int yt = yb[t];
    sum += xb[t * NL + yt];                     // emission gather
    if (t >= 1) sum += A[yt * NL + yb[t - 1]];  // transition gather
  }
#pragma unroll
  for (int off = 32; off >= 1; off >>= 1) sum += __shfl_xor(sum, off);
  if (lane == 0) wsS[bq] = sum;
}

__global__ __launch_bounds__(512, 1) void crf_final_kernel(
    const double* __restrict__ wsZ, const float* __restrict__ wsS,
    float* __restrict__ outNll) {
  __shared__ double sm[NB];
  const int b = threadIdx.x;
  float s = (wsS[4 * b] + wsS[4 * b + 1]) + (wsS[4 * b + 2] + wsS[4 * b + 3]);
  sm[b] = wsZ[b] - (double)s;  // -(emis+trans) + Z
  __syncthreads();
  for (int off = NB / 2; off >= 1; off >>= 1) {
    if (b < off) sm[b] += sm[b + off];
    __syncthreads();
  }
  if (b == 0) outNll[0] = (float)(sm[0] * (1.0 / NB));
}

extern "C" void kernel_launch(void* const* d_in, const int* in_sizes, int n_in,
                              void* d_out, int out_size, void* d_ws,
                              size_t ws_size, hipStream_t stream) {
  const float* x = (const float*)d_in[0];
  const int* y = (const int*)d_in[1];  // harness delivers integers as int32
  const float* A = (const float*)d_in[2];
  float* out = (float*)d_out;   // [B*S] preds-as-float, then nll scalar
  double* wsZ = (double*)d_ws;  // [512] doubles
  float* wsS = (float*)((char*)d_ws + NB * sizeof(double));  // [2048] floats

  crf_fwd_kernel<<<dim3(2 * NB), dim3(64), 0, stream>>>(x, A, out, wsZ);
  crf_gather_kernel<<<dim3(4 * NB), dim3(64), 0, stream>>>(x, y, A, wsS);
  crf_final_kernel<<<dim3(1), dim3(512), 0, stream>>>(wsZ, wsS,
                                                      out + (size_t)NB * NS);
}